// Round 6
// baseline (142.731 us; speedup 1.0000x reference)
//
#include <hip/hip_runtime.h>

// DtN operator, M=64, N=32 RHS. One workgroup (8 waves) per RHS.
// Pipelined PCG (Ghysels-Vanroose): ONE barrier per iteration (dual-dot
// reduction; edge publication piggybacks on the same barrier via parity
// double-buffering). Preconditioner: block-Jacobi over 8-row strips
// (strip == wave), Chebyshev(deg 5) of the strip-truncated operator —
// all shuffles/registers, zero barriers, zero LDS.
// Thread t owns row t>>3, cols 8*(t&7)..+7. Strip w = wave w = rows 8w..8w+7.

#define BLK 512
#define NBP 252
#define CDEG 5          // strip-cheb degree (CDEG-1 strip stencils per apply)
#define MAXOUT 80
#define LDF 68          // padded LDS row stride for final flux staging
#define EROW 72         // edge-row stride (floats)

typedef float v4 __attribute__((ext_vector_type(4)));

static __device__ __forceinline__ float hmf(float x, float y) {
    float d = x + y;
    return d == 0.f ? 0.f : 2.f * x * y / d;
}

// clockwise Dirichlet embedding (top, right, bottom rev, left rev)
static __device__ __forceinline__ float embedf(const float* db, int i, int j) {
    if (i == 0 && j <= 62) return db[j];
    if (j == 63 && i <= 62) return db[63 + i];
    if (i == 63 && j >= 1)  return db[189 - j];
    return db[252 - i];   // j==0, i>=1
}

__global__ __launch_bounds__(BLK, 1) void dtn_pipe(const float* __restrict__ dbc,
                                                   const float* __restrict__ a,
                                                   float* __restrict__ out) {
    __shared__ float P[64 * LDF];
    __shared__ float EG[2][8][2][EROW];     // [parity][strip][top/bot][col]
    __shared__ double redG[2][8], redD[2][8];

    const int t = threadIdx.x, l = t & 63, wid = t >> 6;
    const int row = t >> 3, cb = (t & 7) << 3;
    const int gbase = (row << 6) + cb;
    const float* db = dbc + blockIdx.x * NBP;
    const bool topl = (l < 8), botl = (l >= 56);

    float cE[8], cW[8], cN[8], cS[8], sD[8];
    float rr[8], uu[8], ww[8], xx[8], zz[8], qq[8], ss[8], pp[8], mm[8], nn[8];

    // ---- raw harmonic-mean coefficients + diagonal scale ----
    #pragma unroll
    for (int q = 0; q < 8; ++q) {
        const int gi = gbase + q, i = row, j = cb + q;
        float e = 0, w = 0, n_ = 0, s_ = 0, sv = 0;
        if (i > 0 && i < 63 && j > 0 && j < 63) {
            const float ac = a[gi];
            e  = hmf(ac, a[gi + 1]);
            w  = hmf(a[gi - 1], ac);
            n_ = hmf(a[gi - 64], ac);
            s_ = hmf(ac, a[gi + 64]);
            sv = 1.f / sqrtf(e + w + n_ + s_);
        }
        cE[q] = e; cW[q] = w; cN[q] = n_; cS[q] = s_; sD[q] = sv;
    }

    // ---- r0 = s .* (A_raw u0): u0 nonzero only on boundary ring ----
    #pragma unroll
    for (int q = 0; q < 8; ++q) {
        const int i = row, j = cb + q;
        float acc = 0.f;
        if (sD[q] != 0.f) {
            if (i == 1)  acc += cN[q] * embedf(db, 0, j);
            if (i == 62) acc += cS[q] * embedf(db, 63, j);
            if (j == 1)  acc += cW[q] * embedf(db, i, 0);
            if (j == 62) acc += cE[q] * embedf(db, i, 63);
        }
        rr[q] = sD[q] * acc;
        xx[q] = zz[q] = qq[q] = ss[q] = pp[q] = 0.f;
    }

    auto edge_write = [&](const float* m, int par) {
        if (topl) {
            v4 a0, a1;
            #pragma unroll
            for (int q = 0; q < 4; ++q) { a0[q] = m[q]; a1[q] = m[q + 4]; }
            *(v4*)&EG[par][wid][0][cb] = a0; *(v4*)&EG[par][wid][0][cb + 4] = a1;
        } else if (botl) {
            v4 a0, a1;
            #pragma unroll
            for (int q = 0; q < 4; ++q) { a0[q] = m[q]; a1[q] = m[q + 4]; }
            *(v4*)&EG[par][wid][1][cb] = a0; *(v4*)&EG[par][wid][1][cb + 4] = a1;
        }
    };

    // ---- scale coefficients: c_dir *= sD_i * sD_neighbor (via shuffles+edges) ----
    edge_write(sD, 0);
    __syncthreads();
    {
        float svN[8], svS[8];
        #pragma unroll
        for (int q = 0; q < 8; ++q) { svN[q] = __shfl_up(sD[q], 8, 64); svS[q] = __shfl_down(sD[q], 8, 64); }
        if (topl) {
            const int nw = wid > 0 ? wid - 1 : 0;
            v4 a0 = *(const v4*)&EG[0][nw][1][cb], a1 = *(const v4*)&EG[0][nw][1][cb + 4];
            #pragma unroll
            for (int q = 0; q < 4; ++q) { svN[q] = a0[q]; svN[q + 4] = a1[q]; }
        }
        if (botl) {
            const int sw = wid < 7 ? wid + 1 : 7;
            v4 a0 = *(const v4*)&EG[0][sw][0][cb], a1 = *(const v4*)&EG[0][sw][0][cb + 4];
            #pragma unroll
            for (int q = 0; q < 4; ++q) { svS[q] = a0[q]; svS[q + 4] = a1[q]; }
        }
        const float svW = __shfl_up(sD[7], 1, 64), svE = __shfl_down(sD[0], 1, 64);
        #pragma unroll
        for (int q = 0; q < 8; ++q) {
            const float se = (q == 7) ? svE : sD[q + 1];
            const float sw = (q == 0) ? svW : sD[q - 1];
            cE[q] *= sD[q] * se; cW[q] *= sD[q] * sw;
            cN[q] *= sD[q] * svN[q]; cS[q] *= sD[q] * svS[q];
        }
    }

    // ---- strip-local stencil (shuffles only; strip-external coupling cut) ----
    auto strip_mv = [&](const float* in, float* o) {
        float vN[8], vS[8];
        #pragma unroll
        for (int q = 0; q < 8; ++q) { vN[q] = __shfl_up(in[q], 8, 64); vS[q] = __shfl_down(in[q], 8, 64); }
        const float wW = __shfl_up(in[7], 1, 64), eE = __shfl_down(in[0], 1, 64);
        #pragma unroll
        for (int q = 0; q < 8; ++q) {
            const float n_ = topl ? 0.f : vN[q];
            const float s_ = botl ? 0.f : vS[q];
            const float w_ = (q == 0) ? wW : in[q - 1];
            const float e_ = (q == 7) ? eE : in[q + 1];
            o[q] = in[q] - (cE[q] * e_ + cW[q] * w_ + cN[q] * n_ + cS[q] * s_);
        }
    };

    // ---- strip-cheb preconditioner on [0.03, 2.0] ----
    auto cheb = [&](const float* rin, float* zo) {
        const float thet = 1.015f, delt = 0.985f, sigc = thet / delt;
        float d8[8], tp[8];
        #pragma unroll
        for (int q = 0; q < 8; ++q) { d8[q] = rin[q] * (1.f / thet); zo[q] = d8[q]; }
        float rho = delt / thet;
        #pragma unroll
        for (int k = 2; k <= CDEG; ++k) {
            strip_mv(zo, tp);
            const float rho1 = 1.f / (2.f * sigc - rho);
            const float c1 = rho1 * rho, c2 = 2.f * rho1 / delt;
            #pragma unroll
            for (int q = 0; q < 8; ++q) {
                const float res = rin[q] - tp[q];
                d8[q] = c1 * d8[q] + c2 * res;
                zo[q] += d8[q];
            }
            rho = rho1;
        }
    };

    // ---- global matvec: shuffles + strip-edge rows from LDS ----
    auto global_mv = [&](const float* in, float* o, int par) {
        float vN[8], vS[8];
        #pragma unroll
        for (int q = 0; q < 8; ++q) { vN[q] = __shfl_up(in[q], 8, 64); vS[q] = __shfl_down(in[q], 8, 64); }
        if (topl) {
            const int nw = wid > 0 ? wid - 1 : 0;
            v4 a0 = *(const v4*)&EG[par][nw][1][cb], a1 = *(const v4*)&EG[par][nw][1][cb + 4];
            #pragma unroll
            for (int q = 0; q < 4; ++q) { vN[q] = a0[q]; vN[q + 4] = a1[q]; }
        }
        if (botl) {
            const int sw = wid < 7 ? wid + 1 : 7;
            v4 a0 = *(const v4*)&EG[par][sw][0][cb], a1 = *(const v4*)&EG[par][sw][0][cb + 4];
            #pragma unroll
            for (int q = 0; q < 4; ++q) { vS[q] = a0[q]; vS[q + 4] = a1[q]; }
        }
        const float wW = __shfl_up(in[7], 1, 64), eE = __shfl_down(in[0], 1, 64);
        #pragma unroll
        for (int q = 0; q < 8; ++q) {
            const float w_ = (q == 0) ? wW : in[q - 1];
            const float e_ = (q == 7) ? eE : in[q + 1];
            o[q] = in[q] - (cE[q] * e_ + cW[q] * w_ + cN[q] * vN[q] + cS[q] * vS[q]);
        }
    };

    auto bred2 = [&](double g, double d, int par, double& G, double& D) {
        #pragma unroll
        for (int off = 32; off > 0; off >>= 1) { g += __shfl_down(g, off, 64); d += __shfl_down(d, off, 64); }
        if (l == 0) { redG[par][wid] = g; redD[par][wid] = d; }
        __syncthreads();
        double sg = 0.0, sd = 0.0;
        #pragma unroll
        for (int w2 = 0; w2 < 8; ++w2) { sg += redG[par][w2]; sd += redD[par][w2]; }
        G = sg; D = sd;
    };

    // ---- setup: u0 = M^-1 r0 ; w0 = B u0 ----
    cheb(rr, uu);
    edge_write(uu, 1);
    __syncthreads();
    global_mv(uu, ww, 1);

    // ---- pipelined PCG main loop: ONE barrier per iteration ----
    double gOld = 1.0, aOld = 1.0, gPrev = 1e300, stop = 0.0;
    int epar = 0, stg = 0;

    for (int it = 0; it < MAXOUT; ++it) {
        cheb(ww, mm);                 // m = M^-1 w   (wave-local)
        edge_write(mm, epar);         // publish m edges (visible after barrier)
        double pg = 0.0, pd = 0.0;
        #pragma unroll
        for (int q = 0; q < 8; ++q) { pg += (double)rr[q] * (double)uu[q]; pd += (double)ww[q] * (double)uu[q]; }
        double G, D;
        bred2(pg, pd, epar, G, D);    // the iteration's single barrier
        global_mv(mm, nn, epar);      // n = B m (reads m edges)

        double beta, alpha;
        if (it == 0) {
            if (!(G > 0.0)) break;
            beta = 0.0; alpha = G / D; stop = G * 1e-7;
        } else {
            if (!(G > stop)) break;   // converged (or NaN)
            beta = G / gOld;
            const double den = D - beta * G / aOld;
            if (!(den > 0.0)) break;
            alpha = G / den;
        }
        bool last = false;
        if (it > 0) {
            if (G > 0.95 * gPrev) { if (++stg >= 2) last = true; }
            else stg = 0;
        }
        const float bf = (float)beta, af = (float)alpha;
        #pragma unroll
        for (int q = 0; q < 8; ++q) {
            zz[q] = nn[q] + bf * zz[q];
            qq[q] = mm[q] + bf * qq[q];
            ss[q] = ww[q] + bf * ss[q];
            pp[q] = uu[q] + bf * pp[q];
            xx[q] += af * pp[q];
            rr[q] -= af * ss[q];
            uu[q] -= af * qq[q];
            ww[q] -= af * zz[q];
        }
        gPrev = G; gOld = G; aOld = alpha; epar ^= 1;
        if (last) break;
    }

    // ---- stage final u = sD .* x (interior) / dbc (boundary) into P ----
    __syncthreads();
    #pragma unroll
    for (int q = 0; q < 8; ++q) {
        const int i = row, j = cb + q;
        float uv;
        if (i == 0 || i == 63 || j == 0 || j == 63) uv = embedf(db, i, j);
        else uv = sD[q] * xx[q];
        P[row * LDF + cb + q] = uv;
    }
    __syncthreads();

    // ---- Neumann flux (clockwise) + de-mean ----
    double v = 0.0;
    if (t < NBP) {
        const double Hi = 63.0;
        if (t == 0)        v = (double)a[0]  * 0.5 * (((double)P[0] - P[LDF]) + ((double)P[0] - P[1])) * Hi;
        else if (t <= 62)  v = (double)a[t]  * ((double)P[t] - P[LDF + t]) * Hi;
        else if (t == 63)  v = (double)a[63] * 0.5 * (((double)P[63] - P[LDF + 63]) + ((double)P[63] - P[62])) * Hi;
        else if (t <= 125) { const int i = t - 63;
                             v = (double)a[(i<<6)+63] * ((double)P[i*LDF+63] - P[i*LDF+62]) * Hi; }
        else if (t == 126) v = (double)a[4095] * 0.5 * (((double)P[63*LDF+63] - P[62*LDF+63]) + ((double)P[63*LDF+63] - P[63*LDF+62])) * Hi;
        else if (t <= 188) { const int j = 189 - t;
                             v = (double)a[4032+j] * ((double)P[63*LDF+j] - P[62*LDF+j]) * Hi; }
        else if (t == 189) v = (double)a[4032] * 0.5 * (((double)P[63*LDF] - P[62*LDF]) + ((double)P[63*LDF] - P[63*LDF+1])) * Hi;
        else               { const int i = 252 - t;
                             v = (double)a[i<<6] * ((double)P[i*LDF] - P[i*LDF+1]) * Hi; }
    }
    // final mean reduction (slots are free; all waves aligned by staging barrier)
    {
        double g = v;
        #pragma unroll
        for (int off = 32; off > 0; off >>= 1) g += __shfl_down(g, off, 64);
        if (l == 0) redG[0][wid] = g;
        __syncthreads();
        double tot = 0.0;
        #pragma unroll
        for (int w2 = 0; w2 < 8; ++w2) tot += redG[0][w2];
        if (t < NBP) out[blockIdx.x * NBP + t] = (float)(v - tot * (1.0 / 252.0));
    }
}

extern "C" void kernel_launch(void* const* d_in, const int* in_sizes, int n_in,
                              void* d_out, int out_size, void* d_ws, size_t ws_size,
                              hipStream_t stream) {
    const float* dbc = (const float*)d_in[0];   // (32, 252)
    const float* a   = (const float*)d_in[1];   // (64, 64)
    float* out = (float*)d_out;                 // (32, 252)
    dtn_pipe<<<dim3(32), dim3(BLK), 0, stream>>>(dbc, a, out);
}

// Round 7
// 87.001 us; speedup vs baseline: 1.6406x; 1.6406x over previous
//
#include <hip/hip_runtime.h>

// DtN operator, M=64, N=32 RHS. One workgroup (8 waves) per RHS.
// Pipelined PCG (Ghysels-Vanroose, single fused dual-dot reduction per
// iteration) with GLOBAL Chebyshev(DEG=6) preconditioner on [0.015, 2.0] of
// the symmetrically scaled operator B = D^{-1/2} A D^{-1/2}.
// Thread t owns row t>>3, cols 8*(t&7)..+7 (row-run). Stencil: N/S via
// ds_read_b128 from double-buffered LDS (ZA/ZB by Cheb-step parity),
// E/W via registers + 2 intra-wave shuffles (cross-row pollution is
// masked by zero boundary-column coefficients).
// Barriers: 5 (cheb) + 1 (reduction, also publishes m=z6 in ZB) per iteration.

#define BLK 512
#define NBP 252
#define DEG 6          // even: z1->ZA, z_DEG->ZB (gmv reads ZB)
#define MAXOUT 40
#define LDF 68         // padded LDS row stride (floats): 16B-aligned runs

typedef float v4 __attribute__((ext_vector_type(4)));

static __device__ __forceinline__ float hmf(float x, float y) {
    float d = x + y;
    return d == 0.f ? 0.f : 2.f * x * y / d;
}

// clockwise Dirichlet embedding (top, right, bottom rev, left rev)
static __device__ __forceinline__ float embedf(const float* db, int i, int j) {
    if (i == 0 && j <= 62) return db[j];
    if (j == 63 && i <= 62) return db[63 + i];
    if (i == 63 && j >= 1)  return db[189 - j];
    return db[252 - i];   // j==0, i>=1
}

__global__ __launch_bounds__(BLK, 1) void dtn_gv(const float* __restrict__ dbc,
                                                 const float* __restrict__ a,
                                                 float* __restrict__ out) {
    __shared__ float ZA[64 * LDF], ZB[64 * LDF];
    __shared__ double redG[2][8], redD[2][8];

    const int t = threadIdx.x, l = t & 63, wid = t >> 6;
    const int row = t >> 3, cb = (t & 7) << 3;
    const int gbase = (row << 6) + cb;
    const int base  = row * LDF + cb;
    const float* db = dbc + blockIdx.x * NBP;
    const bool irow = (row >= 1 && row <= 62);

    float cE[8], cW[8], cN[8], cS[8], sD[8];
    float rr[8], uu[8], ww[8], xx[8], zz[8], qq[8], ss[8], pp[8], mm[8], nn[8];

    // ---- raw harmonic-mean coefficients + diagonal scale (registers) ----
    #pragma unroll
    for (int q = 0; q < 8; ++q) {
        const int gi = gbase + q, i = row, j = cb + q;
        float e = 0, w = 0, n_ = 0, s_ = 0, sv = 0;
        if (i > 0 && i < 63 && j > 0 && j < 63) {
            const float ac = a[gi];
            e  = hmf(ac, a[gi + 1]);
            w  = hmf(a[gi - 1], ac);
            n_ = hmf(a[gi - 64], ac);
            s_ = hmf(ac, a[gi + 64]);
            sv = 1.f / sqrtf(e + w + n_ + s_);
        }
        cE[q] = e; cW[q] = w; cN[q] = n_; cS[q] = s_; sD[q] = sv;
    }

    // ---- r0 = s .* (A_IB u_B): boundary-ring contributions, raw coefs ----
    #pragma unroll
    for (int q = 0; q < 8; ++q) {
        const int i = row, j = cb + q;
        float acc = 0.f;
        if (sD[q] != 0.f) {
            if (i == 1)  acc += cN[q] * embedf(db, 0, j);
            if (i == 62) acc += cS[q] * embedf(db, 63, j);
            if (j == 1)  acc += cW[q] * embedf(db, i, 0);
            if (j == 62) acc += cE[q] * embedf(db, i, 63);
        }
        rr[q] = sD[q] * acc;
        xx[q] = zz[q] = qq[q] = ss[q] = pp[q] = 0.f;
    }

    auto store8 = [&](float* Z, const float* v) {
        v4 a0, a1;
        #pragma unroll
        for (int q = 0; q < 4; ++q) { a0[q] = v[q]; a1[q] = v[q + 4]; }
        *(v4*)&Z[base] = a0; *(v4*)&Z[base + 4] = a1;
    };

    // ---- scale coefficients: c_dir *= sD_i * sD_neighbor ----
    // (boundary neighbors have sD=0 -> Dirichlet coupling eliminated)
    store8(ZA, sD);
    __syncthreads();
    {
        const float svW = __shfl_up(sD[7], 1, 64);
        const float svE = __shfl_down(sD[0], 1, 64);
        if (irow) {
            const v4 n0 = *(const v4*)&ZA[base - LDF], n1 = *(const v4*)&ZA[base - LDF + 4];
            const v4 s0 = *(const v4*)&ZA[base + LDF], s1 = *(const v4*)&ZA[base + LDF + 4];
            const float vN[8] = {n0[0],n0[1],n0[2],n0[3],n1[0],n1[1],n1[2],n1[3]};
            const float vS[8] = {s0[0],s0[1],s0[2],s0[3],s1[0],s1[1],s1[2],s1[3]};
            #pragma unroll
            for (int q = 0; q < 8; ++q) {
                const float se = (q == 7) ? svE : sD[q + 1];
                const float sw = (q == 0) ? svW : sD[q - 1];
                cE[q] *= sD[q] * se; cW[q] *= sD[q] * sw;
                cN[q] *= sD[q] * vN[q]; cS[q] *= sD[q] * vS[q];
            }
        }
    }
    __syncthreads();   // ZA (sD) reads complete before cheb's z1 overwrites

    // ---- stencil: o = B in. N/S from LDS buffer Zc, E/W from regs+shuffles.
    auto stencil = [&](const float* Zc, const float* in, float* o) {
        const float wv = __shfl_up(in[7], 1, 64);    // convergent: outside branch
        const float ev = __shfl_down(in[0], 1, 64);
        if (irow) {
            const v4 n0 = *(const v4*)&Zc[base - LDF], n1 = *(const v4*)&Zc[base - LDF + 4];
            const v4 s0 = *(const v4*)&Zc[base + LDF], s1 = *(const v4*)&Zc[base + LDF + 4];
            const float vN[8] = {n0[0],n0[1],n0[2],n0[3],n1[0],n1[1],n1[2],n1[3]};
            const float vS[8] = {s0[0],s0[1],s0[2],s0[3],s1[0],s1[1],s1[2],s1[3]};
            #pragma unroll
            for (int q = 0; q < 8; ++q) {
                const float w_ = (q == 0) ? wv : in[q - 1];
                const float e_ = (q == 7) ? ev : in[q + 1];
                o[q] = in[q] - (cE[q] * e_ + cW[q] * w_ + cN[q] * vN[q] + cS[q] * vS[q]);
            }
        } else {
            #pragma unroll
            for (int q = 0; q < 8; ++q) o[q] = in[q];
        }
    };

    // ---- global Chebyshev preconditioner, [0.015, 2.0] ----
    const float thet = 1.0075f, delt = 0.9925f;
    const float sigc = thet / delt, invthet = 1.f / thet;

    // z_k stores: k odd -> ZA, k even -> ZB. Stencil k reads z_{k-1}'s buffer.
    // 5 barriers; z_DEG lands in ZB, made visible by the caller's next barrier.
    auto cheb = [&](const float* rin, float* zo) {
        float d8[8], tp[8];
        #pragma unroll
        for (int q = 0; q < 8; ++q) { d8[q] = rin[q] * invthet; zo[q] = d8[q]; }
        store8(ZA, zo);                       // z1
        float rho = 1.f / sigc;
        #pragma unroll
        for (int k = 2; k <= DEG; ++k) {
            __syncthreads();
            stencil((k & 1) ? ZB : ZA, zo, tp);
            const float rho1 = 1.f / (2.f * sigc - rho);
            const float c1 = rho1 * rho, c2 = 2.f * rho1 / delt;
            #pragma unroll
            for (int q = 0; q < 8; ++q) { d8[q] = c1 * d8[q] + c2 * (rin[q] - tp[q]); zo[q] += d8[q]; }
            store8((k & 1) ? ZA : ZB, zo);    // z_k
            rho = rho1;
        }
    };

    // ---- setup: u0 = M^-1 r0 ; w0 = B u0 ----
    cheb(rr, uu);
    __syncthreads();          // publish z_DEG (= u0) in ZB
    stencil(ZB, uu, ww);

    // ---- pipelined PCG (GV): 6 barriers/iter, ONE reduction ----
    double gOld = 1.0, aOld = 1.0, gPrev = 1e300, stop = 0.0;
    int epar = 0, stg = 0;

    for (int it = 0; it < MAXOUT; ++it) {
        cheb(ww, mm);                        // m = M^-1 w (ends in ZB + regs)
        double pg = 0.0, pd = 0.0;
        #pragma unroll
        for (int q = 0; q < 8; ++q) { pg += (double)rr[q] * uu[q]; pd += (double)ww[q] * uu[q]; }
        #pragma unroll
        for (int off = 32; off > 0; off >>= 1) {
            pg += __shfl_down(pg, off, 64); pd += __shfl_down(pd, off, 64);
        }
        if (l == 0) { redG[epar][wid] = pg; redD[epar][wid] = pd; }
        __syncthreads();                     // slots + m(ZB) visible
        double G = 0.0, D = 0.0;
        #pragma unroll
        for (int w2 = 0; w2 < 8; ++w2) { G += redG[epar][w2]; D += redD[epar][w2]; }
        stencil(ZB, mm, nn);                 // n = B m

        double beta, alpha;
        if (it == 0) {
            if (!(G > 0.0)) break;
            beta = 0.0; alpha = G / D; stop = G * 1e-7;
        } else {
            if (!(G > stop)) break;          // converged / NaN guard (uniform)
            beta = G / gOld;
            const double den = D - beta * G / aOld;
            if (!(den > 0.0)) break;
            alpha = G / den;
        }
        bool last = false;
        if (it > 0) {
            if (G > 0.97 * gPrev) { if (++stg >= 3) last = true; }
            else stg = 0;
        }
        const float bf = (float)beta, af = (float)alpha;
        #pragma unroll
        for (int q = 0; q < 8; ++q) {
            zz[q] = nn[q] + bf * zz[q];
            qq[q] = mm[q] + bf * qq[q];
            ss[q] = ww[q] + bf * ss[q];
            pp[q] = uu[q] + bf * pp[q];
            xx[q] += af * pp[q];
            rr[q] -= af * ss[q];
            uu[q] -= af * qq[q];
            ww[q] -= af * zz[q];
        }
        gPrev = G; gOld = G; aOld = alpha; epar ^= 1;
        if (last) break;
    }

    // ---- stage final u = sD .* x (interior) / dbc (boundary) into ZA ----
    // (exit is wave-uniform; last barrier passed by all waves was the final
    //  reduction barrier; no pending ZA reads remain.)
    float* P = ZA;
    #pragma unroll
    for (int q = 0; q < 8; ++q) {
        const int i = row, j = cb + q;
        float uv;
        if (i == 0 || i == 63 || j == 0 || j == 63) uv = embedf(db, i, j);
        else uv = sD[q] * xx[q];
        P[base + q] = uv;
    }
    __syncthreads();

    // ---- Neumann flux (clockwise) + de-mean ----
    double v = 0.0;
    if (t < NBP) {
        const double Hi = 63.0;
        if (t == 0)        v = (double)a[0]  * 0.5 * (((double)P[0] - P[LDF]) + ((double)P[0] - P[1])) * Hi;
        else if (t <= 62)  v = (double)a[t]  * ((double)P[t] - P[LDF + t]) * Hi;
        else if (t == 63)  v = (double)a[63] * 0.5 * (((double)P[63] - P[LDF + 63]) + ((double)P[63] - P[62])) * Hi;
        else if (t <= 125) { const int i = t - 63;
                             v = (double)a[(i<<6)+63] * ((double)P[i*LDF+63] - P[i*LDF+62]) * Hi; }
        else if (t == 126) v = (double)a[4095] * 0.5 * (((double)P[63*LDF+63] - P[62*LDF+63]) + ((double)P[63*LDF+63] - P[63*LDF+62])) * Hi;
        else if (t <= 188) { const int j = 189 - t;
                             v = (double)a[4032+j] * ((double)P[63*LDF+j] - P[62*LDF+j]) * Hi; }
        else if (t == 189) v = (double)a[4032] * 0.5 * (((double)P[63*LDF] - P[62*LDF]) + ((double)P[63*LDF] - P[63*LDF+1])) * Hi;
        else               { const int i = 252 - t;
                             v = (double)a[i<<6] * ((double)P[i*LDF] - P[i*LDF+1]) * Hi; }
    }
    {
        double g = v;
        #pragma unroll
        for (int off = 32; off > 0; off >>= 1) g += __shfl_down(g, off, 64);
        if (l == 0) redG[0][wid] = g;
        __syncthreads();
        double tot = 0.0;
        #pragma unroll
        for (int w2 = 0; w2 < 8; ++w2) tot += redG[0][w2];
        if (t < NBP) out[blockIdx.x * NBP + t] = (float)(v - tot * (1.0 / 252.0));
    }
}

extern "C" void kernel_launch(void* const* d_in, const int* in_sizes, int n_in,
                              void* d_out, int out_size, void* d_ws, size_t ws_size,
                              hipStream_t stream) {
    const float* dbc = (const float*)d_in[0];   // (32, 252)
    const float* a   = (const float*)d_in[1];   // (64, 64)
    float* out = (float*)d_out;                 // (32, 252)
    dtn_gv<<<dim3(32), dim3(BLK), 0, stream>>>(dbc, a, out);
}

// Round 8
// 73.717 us; speedup vs baseline: 1.9362x; 1.1802x over previous
//
#include <hip/hip_runtime.h>

// DtN operator, M=64, N=32 RHS. One workgroup (8 waves) per RHS.
// Pipelined PCG (Ghysels-Vanroose, single fused dual-dot reduction per
// iteration) with global Chebyshev(DEG=6) preconditioner on [0.015, 2.0] of
// B = D^{-1/2} A D^{-1/2}. Thread t owns a 2x4 patch: rows {2rp, 2rp+1},
// cols 4*(t&15)..+3  (rp = t>>4). Intra-patch N/S are register-local;
// only N-of-top and S-of-bottom come from LDS (2 x b128 per stencil, was 4).
// E/W via intra-wave shuffles, wave/row-crossing garbage masked by zero
// boundary coefficients. Boundary points have all-zero coefs -> identity
// rows, no divergent branch. LDS stride 68 floats (16B-aligned, bank-uniform).

#define BLK 512
#define NBP 252
#define DEG 6          // even: z1->ZA, z_DEG->ZB (gmv reads ZB)
#define MAXOUT 40
#define LDF 68

typedef float v4 __attribute__((ext_vector_type(4)));

static __device__ __forceinline__ float hmf(float x, float y) {
    float d = x + y;
    return d == 0.f ? 0.f : 2.f * x * y / d;
}

// clockwise Dirichlet embedding (top, right, bottom rev, left rev)
static __device__ __forceinline__ float embedf(const float* db, int i, int j) {
    if (i == 0 && j <= 62) return db[j];
    if (j == 63 && i <= 62) return db[63 + i];
    if (i == 63 && j >= 1)  return db[189 - j];
    return db[252 - i];   // j==0, i>=1
}

__global__ __launch_bounds__(BLK, 1) void dtn_gv(const float* __restrict__ dbc,
                                                 const float* __restrict__ a,
                                                 float* __restrict__ out) {
    __shared__ float ZA[64 * LDF], ZB[64 * LDF];
    __shared__ double redG[2][8], redD[2][8];

    const int t = threadIdx.x, l = t & 63, wid = t >> 6;
    const int rp = t >> 4;                 // row pair 0..31
    const int r0 = rp << 1, r1 = r0 + 1;
    const int cq = (t & 15) << 2;          // col base 0..60
    const int b0 = r0 * LDF + cq, b1 = r1 * LDF + cq;
    const int bn = (rp == 0 ? r0 : r0 - 1) * LDF + cq;    // N row of r0 (clamped)
    const int bs = (rp == 31 ? r1 : r1 + 1) * LDF + cq;   // S row of r1 (clamped)
    const float* db = dbc + blockIdx.x * NBP;

    float cE[8], cW[8], cN[8], cS[8], sD[8];
    float rr[8], uu[8], ww[8], xx[8], zz[8], qq[8], ss[8], pp[8], mm[8], nn[8];

    // ---- raw harmonic-mean coefficients + diagonal scale (registers) ----
    #pragma unroll
    for (int p = 0; p < 8; ++p) {
        const int i = (p < 4) ? r0 : r1, j = cq + (p & 3), gi = (i << 6) + j;
        float e = 0, w = 0, n_ = 0, s_ = 0, sv = 0;
        if (i > 0 && i < 63 && j > 0 && j < 63) {
            const float ac = a[gi];
            e  = hmf(ac, a[gi + 1]);
            w  = hmf(a[gi - 1], ac);
            n_ = hmf(a[gi - 64], ac);
            s_ = hmf(ac, a[gi + 64]);
            sv = 1.f / sqrtf(e + w + n_ + s_);
        }
        cE[p] = e; cW[p] = w; cN[p] = n_; cS[p] = s_; sD[p] = sv;
    }

    // ---- r0 = s .* (A_IB u_B): boundary-ring contributions, raw coefs ----
    #pragma unroll
    for (int p = 0; p < 8; ++p) {
        const int i = (p < 4) ? r0 : r1, j = cq + (p & 3);
        float acc = 0.f;
        if (sD[p] != 0.f) {
            if (i == 1)  acc += cN[p] * embedf(db, 0, j);
            if (i == 62) acc += cS[p] * embedf(db, 63, j);
            if (j == 1)  acc += cW[p] * embedf(db, i, 0);
            if (j == 62) acc += cE[p] * embedf(db, i, 63);
        }
        rr[p] = sD[p] * acc;
        xx[p] = zz[p] = qq[p] = ss[p] = pp[p] = 0.f;
    }

    auto store8 = [&](float* Z, const float* v) {
        v4 a0, a1;
        #pragma unroll
        for (int c = 0; c < 4; ++c) { a0[c] = v[c]; a1[c] = v[c + 4]; }
        *(v4*)&Z[b0] = a0; *(v4*)&Z[b1] = a1;
    };

    // ---- scale coefficients: c_dir *= sD_i * sD_neighbor ----
    // (boundary neighbors have sD=0 -> Dirichlet coupling eliminated)
    store8(ZA, sD);
    __syncthreads();
    {
        const float sw0 = __shfl_up(sD[3], 1, 64), se0 = __shfl_down(sD[0], 1, 64);
        const float sw1 = __shfl_up(sD[7], 1, 64), se1 = __shfl_down(sD[4], 1, 64);
        const v4 nv = *(const v4*)&ZA[bn];
        const v4 sv_ = *(const v4*)&ZA[bs];
        #pragma unroll
        for (int p = 0; p < 8; ++p) {
            const int c = p & 3;
            const float sn = (p < 4) ? nv[c]     : sD[p - 4];
            const float sb = (p < 4) ? sD[p + 4] : sv_[c];
            const float sw = (c == 0) ? ((p < 4) ? sw0 : sw1) : sD[p - 1];
            const float se = (c == 3) ? ((p < 4) ? se0 : se1) : sD[p + 1];
            cN[p] *= sD[p] * sn; cS[p] *= sD[p] * sb;
            cW[p] *= sD[p] * sw; cE[p] *= sD[p] * se;
        }
    }
    __syncthreads();   // ZA (sD) reads complete before cheb's z1 overwrites

    // ---- stencil: o = B in. N-of-top/S-of-bottom from LDS, rest registers.
    auto stencil = [&](const float* Zc, const float* in, float* o) {
        const float w0 = __shfl_up(in[3], 1, 64), e0 = __shfl_down(in[0], 1, 64);
        const float w1 = __shfl_up(in[7], 1, 64), e1 = __shfl_down(in[4], 1, 64);
        const v4 nv = *(const v4*)&Zc[bn];
        const v4 sv_ = *(const v4*)&Zc[bs];
        #pragma unroll
        for (int p = 0; p < 8; ++p) {
            const int c = p & 3;
            const float n_ = (p < 4) ? nv[c]     : in[p - 4];
            const float s_ = (p < 4) ? in[p + 4] : sv_[c];
            const float w_ = (c == 0) ? ((p < 4) ? w0 : w1) : in[p - 1];
            const float e_ = (c == 3) ? ((p < 4) ? e0 : e1) : in[p + 1];
            o[p] = in[p] - (cE[p] * e_ + cW[p] * w_ + cN[p] * n_ + cS[p] * s_);
        }
    };

    // ---- global Chebyshev preconditioner, [0.015, 2.0] ----
    const float thet = 1.0075f, delt = 0.9925f;
    const float sigc = thet / delt, invthet = 1.f / thet;

    // z_k stores: k odd -> ZA, k even -> ZB. Stencil k reads z_{k-1}'s buffer.
    auto cheb = [&](const float* rin, float* zo) {
        float d8[8], tp[8];
        #pragma unroll
        for (int p = 0; p < 8; ++p) { d8[p] = rin[p] * invthet; zo[p] = d8[p]; }
        store8(ZA, zo);                       // z1
        float rho = 1.f / sigc;
        #pragma unroll
        for (int k = 2; k <= DEG; ++k) {
            __syncthreads();
            stencil((k & 1) ? ZB : ZA, zo, tp);
            const float rho1 = 1.f / (2.f * sigc - rho);
            const float c1 = rho1 * rho, c2 = 2.f * rho1 / delt;
            #pragma unroll
            for (int p = 0; p < 8; ++p) { d8[p] = c1 * d8[p] + c2 * (rin[p] - tp[p]); zo[p] += d8[p]; }
            store8((k & 1) ? ZA : ZB, zo);    // z_k
            rho = rho1;
        }
    };

    // ---- setup: u0 = M^-1 r0 ; w0 = B u0 ----
    cheb(rr, uu);
    __syncthreads();          // publish z_DEG (= u0) in ZB
    stencil(ZB, uu, ww);

    // ---- pipelined PCG (GV): 6 barriers/iter, ONE fused reduction ----
    double gOld = 1.0, aOld = 1.0, gPrev = 1e300, stop = 0.0;
    int epar = 0, stg = 0;

    for (int it = 0; it < MAXOUT; ++it) {
        cheb(ww, mm);                        // m = M^-1 w (ends in ZB + regs)
        double pg = 0.0, pd = 0.0;
        #pragma unroll
        for (int p = 0; p < 8; ++p) { pg += (double)rr[p] * uu[p]; pd += (double)ww[p] * uu[p]; }
        #pragma unroll
        for (int off = 32; off > 0; off >>= 1) {
            pg += __shfl_down(pg, off, 64); pd += __shfl_down(pd, off, 64);
        }
        if (l == 0) { redG[epar][wid] = pg; redD[epar][wid] = pd; }
        __syncthreads();                     // slots + m(ZB) visible
        double G = 0.0, D = 0.0;
        #pragma unroll
        for (int w2 = 0; w2 < 8; ++w2) { G += redG[epar][w2]; D += redD[epar][w2]; }
        stencil(ZB, mm, nn);                 // n = B m

        double beta, alpha;
        if (it == 0) {
            if (!(G > 0.0)) break;
            beta = 0.0; alpha = G / D; stop = G * 1e-6;
        } else {
            if (!(G > stop)) break;          // converged / NaN guard (uniform)
            beta = G / gOld;
            const double den = D - beta * G / aOld;
            if (!(den > 0.0)) break;
            alpha = G / den;
        }
        bool last = false;
        if (it > 0) {
            if (G > 0.97 * gPrev) { if (++stg >= 3) last = true; }
            else stg = 0;
        }
        const float bf = (float)beta, af = (float)alpha;
        #pragma unroll
        for (int p = 0; p < 8; ++p) {
            zz[p] = nn[p] + bf * zz[p];
            qq[p] = mm[p] + bf * qq[p];
            ss[p] = ww[p] + bf * ss[p];
            pp[p] = uu[p] + bf * pp[p];
            xx[p] += af * pp[p];
            rr[p] -= af * ss[p];
            uu[p] -= af * qq[p];
            ww[p] -= af * zz[p];
        }
        gPrev = G; gOld = G; aOld = alpha; epar ^= 1;
        if (last) break;
    }

    // ---- stage final u = sD .* x (interior) / dbc (boundary) into ZA ----
    // (exit wave-uniform; all prior ZA reads were pre-reduction-barrier)
    float* P = ZA;
    {
        float fu[8];
        #pragma unroll
        for (int p = 0; p < 8; ++p) {
            const int i = (p < 4) ? r0 : r1, j = cq + (p & 3);
            if (i == 0 || i == 63 || j == 0 || j == 63) fu[p] = embedf(db, i, j);
            else fu[p] = sD[p] * xx[p];
        }
        store8(ZA, fu);
    }
    __syncthreads();

    // ---- Neumann flux (clockwise) + de-mean ----
    double v = 0.0;
    if (t < NBP) {
        const double Hi = 63.0;
        if (t == 0)        v = (double)a[0]  * 0.5 * (((double)P[0] - P[LDF]) + ((double)P[0] - P[1])) * Hi;
        else if (t <= 62)  v = (double)a[t]  * ((double)P[t] - P[LDF + t]) * Hi;
        else if (t == 63)  v = (double)a[63] * 0.5 * (((double)P[63] - P[LDF + 63]) + ((double)P[63] - P[62])) * Hi;
        else if (t <= 125) { const int i = t - 63;
                             v = (double)a[(i<<6)+63] * ((double)P[i*LDF+63] - P[i*LDF+62]) * Hi; }
        else if (t == 126) v = (double)a[4095] * 0.5 * (((double)P[63*LDF+63] - P[62*LDF+63]) + ((double)P[63*LDF+63] - P[63*LDF+62])) * Hi;
        else if (t <= 188) { const int j = 189 - t;
                             v = (double)a[4032+j] * ((double)P[63*LDF+j] - P[62*LDF+j]) * Hi; }
        else if (t == 189) v = (double)a[4032] * 0.5 * (((double)P[63*LDF] - P[62*LDF]) + ((double)P[63*LDF] - P[63*LDF+1])) * Hi;
        else               { const int i = 252 - t;
                             v = (double)a[i<<6] * ((double)P[i*LDF] - P[i*LDF+1]) * Hi; }
    }
    {
        double g = v;
        #pragma unroll
        for (int off = 32; off > 0; off >>= 1) g += __shfl_down(g, off, 64);
        if (l == 0) redG[0][wid] = g;
        __syncthreads();
        double tot = 0.0;
        #pragma unroll
        for (int w2 = 0; w2 < 8; ++w2) tot += redG[0][w2];
        if (t < NBP) out[blockIdx.x * NBP + t] = (float)(v - tot * (1.0 / 252.0));
    }
}

extern "C" void kernel_launch(void* const* d_in, const int* in_sizes, int n_in,
                              void* d_out, int out_size, void* d_ws, size_t ws_size,
                              hipStream_t stream) {
    const float* dbc = (const float*)d_in[0];   // (32, 252)
    const float* a   = (const float*)d_in[1];   // (64, 64)
    float* out = (float*)d_out;                 // (32, 252)
    dtn_gv<<<dim3(32), dim3(BLK), 0, stream>>>(dbc, a, out);
}